// Round 20
// baseline (67.412 us; speedup 1.0000x reference)
//
#include <hip/hip_runtime.h>
#include <math.h>

#define NN 8192
#define DD 512
#define MM 4
#define EE 131072
#define NB 8    // 16-pair batches per block; 2048 blocks x 128 pairs

typedef float  floatx2 __attribute__((ext_vector_type(2)));
typedef _Float16 h2    __attribute__((ext_vector_type(2)));
typedef _Float16 f16x8 __attribute__((ext_vector_type(8)));
typedef float  f32x4   __attribute__((ext_vector_type(4)));

#define K214 0x74007400u   // h2(16384.0, 16384.0) = 2^14 per lane

union F8U { f16x8 v; h2 h[4]; unsigned u[4]; };

__device__ inline h2 pkrtz(float a, float b) {
    return __builtin_bit_cast(h2, __builtin_amdgcn_cvt_pkrtz(a, b));
}

__device__ inline float fdot2a(h2 a, h2 b, float c) {
#if __has_builtin(__builtin_amdgcn_fdot2)
    return __builtin_amdgcn_fdot2(a, b, c, false);
#else
    return c + (float)a[0] * (float)b[0] + (float)a[1] * (float)b[1];
#endif
}

// fp4 e2m1 dequant bit-trick: nibble (s e1 e0 m) -> f16 bits (s<<15)|(eem<<9)
// gives value * 2^-14 EXACTLY (0.5 -> f16 denormal 2^-15).
// u32 of 8 nibbles -> 4 h2 raw pairs; pairing (k, k+4).
__device__ inline void deq4raw(unsigned v, h2 r[4]) {
    #pragma unroll
    for (int k = 0; k < 4; ++k) {
        unsigned t = v >> (4 * k);
        unsigned x = ((t & 0x00070007u) << 9) | ((t & 0x00080008u) << 12);
        r[k] = __builtin_bit_cast(h2, x);
    }
}

template <int CTRL>
__device__ inline float dpp_add(float v) {
    int x = __builtin_amdgcn_update_dpp(0, __builtin_bit_cast(int, v), CTRL, 0xf, 0xf, true);
    return v + __builtin_bit_cast(float, x);
}

// Async global->LDS: per-lane global src, uniform LDS base (+lane*16 in HW).
__device__ inline void dma16(const void* g, void* l) {
    __builtin_amdgcn_global_load_lds(
        (const __attribute__((address_space(1))) void*)g,
        (__attribute__((address_space(3))) void*)l, 16, 0, 0);
}

// ---------------------------------------------------------------------------
// Kernel 1 (r19-verified, unchanged): fp4 e2m1 table (nibble/dim, 256B/row),
// midpoint-ladder quantizer; reciprocal norms from the SAME dequantized f16
// values and pk_mul chain as the pair kernel. rn_t[m][n] carries the 2^7
// scale that cancels against acc's 2^-14 in the pair epilogue. Zeroes out.
// ---------------------------------------------------------------------------
__global__ __launch_bounds__(256) void quant_norm_kernel(const float* __restrict__ emb,
                                                         const float* __restrict__ mh,
                                                         unsigned* __restrict__ q4,
                                                         float* __restrict__ rn_t,
                                                         float* __restrict__ out) {
    if (blockIdx.x == 0 && threadIdx.x == 0) out[0] = 0.0f;

    const int lane = threadIdx.x & 63;
    const unsigned n = blockIdx.x * 4 + (threadIdx.x >> 6);

    const float* er = emb + n * DD + lane * 8;
    float4 e0 = *(const float4*)(er);
    float4 e1 = *(const float4*)(er + 4);
    float xv[8] = {e0.x, e0.y, e0.z, e0.w, e1.x, e1.y, e1.z, e1.w};

    unsigned pack = 0;
    #pragma unroll
    for (int k = 0; k < 8; ++k) {
        float a = fabsf(xv[k]);
        unsigned mag = (unsigned)(a >= 0.25f) + (a >= 0.75f) + (a >= 1.25f) +
                       (a >= 1.75f) + (a >= 2.5f) + (a >= 3.5f) + (a >= 5.0f);
        unsigned nib = mag | ((__builtin_bit_cast(unsigned, xv[k]) >> 28) & 8u);
        pack |= nib << (4 * k);
    }
    q4[(n << 6) | lane] = pack;

    h2 raw[4];
    deq4raw(pack, raw);
    const h2 K = __builtin_bit_cast(h2, K214);
    h2 prs[4];
    #pragma unroll
    for (int k = 0; k < 4; ++k) {
        h2 full = raw[k] * K;
        prs[k] = full * raw[k];
    }

    const float* mb = mh + lane * 8;
    float ss[4];
    #pragma unroll
    for (int m = 0; m < 4; ++m) {
        float4 m0 = *(const float4*)(mb + m * DD);
        float4 m1 = *(const float4*)(mb + m * DD + 4);
        h2 w0 = pkrtz(m0.x * m0.x, m1.x * m1.x);
        h2 w1 = pkrtz(m0.y * m0.y, m1.y * m1.y);
        h2 w2 = pkrtz(m0.z * m0.z, m1.z * m1.z);
        h2 w3 = pkrtz(m0.w * m0.w, m1.w * m1.w);
        float s = 0.f;
        s = fdot2a(prs[0], w0, s);
        s = fdot2a(prs[1], w1, s);
        s = fdot2a(prs[2], w2, s);
        s = fdot2a(prs[3], w3, s);
        ss[m] = s;
    }

    ss[0] = dpp_add<0x111>(ss[0]); ss[1] = dpp_add<0x111>(ss[1]);
    ss[2] = dpp_add<0x111>(ss[2]); ss[3] = dpp_add<0x111>(ss[3]);
    ss[0] = dpp_add<0x112>(ss[0]); ss[1] = dpp_add<0x112>(ss[1]);
    ss[2] = dpp_add<0x112>(ss[2]); ss[3] = dpp_add<0x112>(ss[3]);
    ss[0] = dpp_add<0x114>(ss[0]); ss[1] = dpp_add<0x114>(ss[1]);
    ss[2] = dpp_add<0x114>(ss[2]); ss[3] = dpp_add<0x114>(ss[3]);
    ss[0] = dpp_add<0x118>(ss[0]); ss[1] = dpp_add<0x118>(ss[1]);
    ss[2] = dpp_add<0x118>(ss[2]); ss[3] = dpp_add<0x118>(ss[3]);
    ss[0] = dpp_add<0x142>(ss[0]); ss[1] = dpp_add<0x142>(ss[1]);
    ss[2] = dpp_add<0x142>(ss[2]); ss[3] = dpp_add<0x142>(ss[3]);
    ss[0] = dpp_add<0x143>(ss[0]); ss[1] = dpp_add<0x143>(ss[1]);
    ss[2] = dpp_add<0x143>(ss[2]); ss[3] = dpp_add<0x143>(ss[3]);

    if (lane == 63) {
        rn_t[0 * NN + n] = 1.0f / fmaxf(sqrtf(ss[0]), 1e-12f);
        rn_t[1 * NN + n] = 1.0f / fmaxf(sqrtf(ss[1]), 1e-12f);
        rn_t[2 * NN + n] = 1.0f / fmaxf(sqrtf(ss[2]), 1e-12f);
        rn_t[3 * NN + n] = 1.0f / fmaxf(sqrtf(ss[3]), 1e-12f);
    }
}

// ---------------------------------------------------------------------------
// Kernel 2: r19 data path + schedule, ONE variable changed: occupancy.
//  - NB=8 -> 2048 blocks (8/CU desired)
//  - B-weights in 16 VGPRs/wave (own mf-quarter; fp4 (k,k+4) pairing:
//    bw[mq].h[j] = f16(mh[m][w*128+mq*32+kq*8+j]^2, mh[m][..+4+j]^2) —
//    matches deq4raw's r[k]=(dim k, dim k+4) and r19's wlds pairing)
//  - wlds + initial __syncthreads removed -> LDS 20KB = 8 blocks/CU
// ---------------------------------------------------------------------------
__global__ __launch_bounds__(256) void pair_kernel(const int* __restrict__ edges,
                                                   const int* __restrict__ nedges,
                                                   const unsigned char* __restrict__ qtab,
                                                   const float* __restrict__ mh,
                                                   const float* __restrict__ rn_t,
                                                   float* __restrict__ out) {
    __shared__ __align__(16) unsigned char sbuf[2][8192];    // 16 KiB
    __shared__ __align__(16) float xchg[4][64][4];           // 4 KiB

    const int t    = threadIdx.x;
    const int lane = t & 63;
    const int w    = t >> 6;      // wave id = k-quarter
    const int p    = lane & 15;   // pair-row / B-col
    const int kq   = lane >> 4;   // k-quad within MFMA
    const int m    = p & 3;

    // B-weights in registers, own quarter, fp4 (k,k+4) pairing:
    const float* wsrc = mh + m * DD + w * 128 + kq * 8;
    f16x8 bw[4];
    #pragma unroll
    for (int mq = 0; mq < 4; ++mq) {
        float4 m0 = *(const float4*)(wsrc + mq * 32);
        float4 m1 = *(const float4*)(wsrc + mq * 32 + 4);
        F8U tw;
        tw.h[0] = pkrtz(m0.x * m0.x, m1.x * m1.x);
        tw.h[1] = pkrtz(m0.y * m0.y, m1.y * m1.y);
        tw.h[2] = pkrtz(m0.z * m0.z, m1.z * m1.z);
        tw.h[3] = pkrtz(m0.w * m0.w, m1.w * m1.w);
        bw[mq] = tw.v;
    }

    const float* rm = rn_t + m * NN;
    const h2 K = __builtin_bit_cast(h2, K214);

    const int  bbase = blockIdx.x * (NB * 16);
    const bool pos   = bbase < EE;
    const int* eb    = pos ? edges : nedges;
    const int  lb    = pos ? bbase : bbase - EE;

    // prologue: batch 0 DMA (wave w stages pairs 4w..4w+3 via 2 DMAs)
    #pragma unroll
    for (int du = 0; du < 2; ++du) {
        int u  = w * 2 + du;
        int pA = u * 2, pB = u * 2 + 1;
        int iA = eb[lb + pA], jA = eb[lb + EE + pA];
        int iB = eb[lb + pB], jB = eb[lb + EE + pB];
        int row = (lane < 16) ? iA : (lane < 32) ? jA : (lane < 48) ? iB : jB;
        int pg  = (lane < 32) ? pA : pB;
        const unsigned char* src = qtab + ((size_t)(unsigned)row << 8)
                                 + (((lane & 15) ^ pg) << 4);
        dma16(src, &sbuf[0][u * 1024]);
    }

    float lsum = 0.f;

    #pragma unroll 1
    for (int bt = 0; bt < NB; ++bt) {
        const int lb2 = lb + bt * 16;

        // wave 0: epilogue operands for THIS batch (dependent chain BEFORE
        // next DMA issue — r14/r19 ordering, r15/r17 lesson)
        float rw0 = 0.f, rw1 = 0.f, rw2 = 0.f, rw3 = 0.f;
        if (w == 0) {
            int4 pi4 = *(const int4*)(eb + lb2 + kq * 4);
            int4 pj4 = *(const int4*)(eb + lb2 + EE + kq * 4);
            rw0 = rm[pi4.x] * rm[pj4.x];
            rw1 = rm[pi4.y] * rm[pj4.y];
            rw2 = rm[pi4.z] * rm[pj4.z];
            rw3 = rm[pi4.w] * rm[pj4.w];
        }

        // next-batch DMA into the other buffer
        if (bt + 1 < NB) {
            const int nlb = lb + (bt + 1) * 16;
            unsigned char* dst = sbuf[(bt + 1) & 1];
            #pragma unroll
            for (int du = 0; du < 2; ++du) {
                int u  = w * 2 + du;
                int pA = u * 2, pB = u * 2 + 1;
                int iA = eb[nlb + pA], jA = eb[nlb + EE + pA];
                int iB = eb[nlb + pB], jB = eb[nlb + EE + pB];
                int row = (lane < 16) ? iA : (lane < 32) ? jA : (lane < 48) ? iB : jB;
                int pg  = (lane < 32) ? pA : pB;
                const unsigned char* src = qtab + ((size_t)(unsigned)row << 8)
                                         + (((lane & 15) ^ pg) << 4);
                dma16(src, &dst[u * 1024]);
            }
            asm volatile("s_waitcnt vmcnt(2)" ::: "memory");
        } else {
            asm volatile("s_waitcnt vmcnt(0)" ::: "memory");
        }
        __builtin_amdgcn_sched_barrier(0);
        asm volatile("s_waitcnt lgkmcnt(0)" ::: "memory");
        __builtin_amdgcn_s_barrier();          // #1: batch bt data ready

        // compute: wave w handles mf = 4w .. 4w+3
        const unsigned char* bb = sbuf[bt & 1];
        f32x4 acc = {0.f, 0.f, 0.f, 0.f};
        #pragma unroll
        for (int mq = 0; mq < 4; ++mq) {
            int mf = w * 4 + mq;
            unsigned ioff = (unsigned)(p * 512 + (((mf ^ p) & 15) << 4) + kq * 4);
            unsigned ua = *(const unsigned*)(bb + ioff);
            unsigned ub = *(const unsigned*)(bb + ioff + 256);
            h2 ra[4], rb[4];
            deq4raw(ua, ra);
            deq4raw(ub, rb);
            F8U pr;
            #pragma unroll
            for (int k = 0; k < 4; ++k) {
                h2 fa = ra[k] * K;        // a (true value)
                pr.h[k] = fa * rb[k];     // a*b*2^-14, exact in f16
            }
            acc = __builtin_amdgcn_mfma_f32_16x16x32_f16(pr.v, bw[mq], acc, 0, 0, 0);
        }

        // exchange partial accumulators
        *(float4*)(&xchg[w][lane][0]) = make_float4(acc[0], acc[1], acc[2], acc[3]);
        asm volatile("s_waitcnt lgkmcnt(0)" ::: "memory");
        __builtin_amdgcn_s_barrier();          // #2: partials visible

        if (w == 0) {
            float4 x0 = *(const float4*)(&xchg[0][lane][0]);
            float4 x1 = *(const float4*)(&xchg[1][lane][0]);
            float4 x2 = *(const float4*)(&xchg[2][lane][0]);
            float4 x3 = *(const float4*)(&xchg[3][lane][0]);
            asm volatile("s_waitcnt lgkmcnt(0)" ::: "memory");
            __builtin_amdgcn_sched_barrier(0);

            // acc carries 2^-14; rw carries 2^14 (rn from ss*2^-14) — cancels
            float v0 = (x0.x + x1.x + x2.x + x3.x) * rw0;
            float v1 = (x0.y + x1.y + x2.y + x3.y) * rw1;
            float v2 = (x0.z + x1.z + x2.z + x3.z) * rw2;
            float v3 = (x0.w + x1.w + x2.w + x3.w) * rw3;
            v0 = dpp_add<0x111>(v0); v1 = dpp_add<0x111>(v1);
            v2 = dpp_add<0x112>(dpp_add<0x111>(v2));
            v0 = dpp_add<0x112>(v0); v1 = dpp_add<0x112>(v1);
            v3 = dpp_add<0x112>(dpp_add<0x111>(v3));
            // lane p==3 (per kq row) holds full m-sums for pairs kq*4 + 0..3

            float d0 = 1.000001f - 0.25f * v0;
            float d1 = 1.000001f - 0.25f * v1;
            float d2 = 1.000001f - 0.25f * v2;
            float d3 = 1.000001f - 0.25f * v3;
            float a0 = pos ? d0 : fmaf(-0.5f, d0, 1.0f);
            float a1 = pos ? d1 : fmaf(-0.5f, d1, 1.0f);
            float a2 = pos ? d2 : fmaf(-0.5f, d2, 1.0f);
            float a3 = pos ? d3 : fmaf(-0.5f, d3, 1.0f);
            float lg = __logf(fmaxf(a0, 1e-8f)) + __logf(fmaxf(a1, 1e-8f)) +
                       __logf(fmaxf(a2, 1e-8f)) + __logf(fmaxf(a3, 1e-8f));
            lsum += (p == 3) ? lg : 0.f;
        }
        __builtin_amdgcn_s_barrier();          // B: xchg/buf safe to reuse
    }

    if (w == 0) {
        lsum = dpp_add<0x111>(lsum);
        lsum = dpp_add<0x112>(lsum);
        lsum = dpp_add<0x114>(lsum);
        lsum = dpp_add<0x118>(lsum);
        lsum = dpp_add<0x142>(lsum);
        lsum = dpp_add<0x143>(lsum);
        if (lane == 63) atomicAdd(out, -lsum);
    }
}

extern "C" void kernel_launch(void* const* d_in, const int* in_sizes, int n_in,
                              void* d_out, int out_size, void* d_ws, size_t ws_size,
                              hipStream_t stream) {
    const int*   edges  = (const int*)d_in[0];
    const int*   nedges = (const int*)d_in[1];
    const float* emb    = (const float*)d_in[2];
    const float* mh     = (const float*)d_in[3];
    float* out = (float*)d_out;

    unsigned* q4   = (unsigned*)d_ws;                             // 2 MiB fp4 table
    float*    rn_t = (float*)((char*)d_ws + (size_t)NN * DD / 2); // 128 KiB, [m][n]

    quant_norm_kernel<<<NN / 4, 256, 0, stream>>>(emb, mh, q4, rn_t, out);
    pair_kernel<<<(2 * EE) / (NB * 16), 256, 0, stream>>>(edges, nedges,
                                                          (const unsigned char*)q4,
                                                          mh, rn_t, out);
}